// Round 15
// baseline (608.856 us; speedup 1.0000x reference)
//
#include <hip/hip_runtime.h>
#include <hip/hip_bf16.h>
#include <hip/hip_cooperative_groups.h>
#include <math.h>

namespace cg = cooperative_groups;

#define N_NODES  50000
#define N_EDGES  800000
#define IN_DIM   128
#define HID      256
#define FC1      1024
#define FC2      512
#define N_ACT    16
#define N_AGENTS 8192

#define BK       32
#define LDK      40
#define BM 128
#define BN 128

#define PREP1_BLOCKS ((N_EDGES + 255) / 256)    // 3125
#define WTR_BLOCKS   208

typedef short bf16x8 __attribute__((ext_vector_type(8)));
typedef float floatx4 __attribute__((ext_vector_type(4)));

__device__ __forceinline__ unsigned short f2b(float f) {
    union { float f; unsigned int i; } v;
    v.f = f;
    unsigned int lsb = (v.i >> 16) & 1u;
    v.i += 0x7fffu + lsb;            // round-to-nearest-even
    return (unsigned short)(v.i >> 16);
}

__device__ __forceinline__ float b2f(unsigned short u) {
    union { unsigned int i; float f; } v;
    v.i = ((unsigned int)u) << 16;
    return v.f;
}

// ===================== shared device helpers (both paths) =====================

__device__ __forceinline__ void gemm64_tile(int tm, int tn,
    const unsigned short* __restrict__ A, const unsigned short* __restrict__ Bt,
    const float* __restrict__ bias, unsigned short* __restrict__ outb,
    int N, int K, int mode,
    unsigned short (*As)[LDK], unsigned short (*Bs)[LDK]) {
    int tid = threadIdx.x;
    int lane = tid & 63, wave = tid >> 6;
    int r16 = lane & 15, quad = lane >> 4;
    int srow = tid >> 2, scol = (tid & 3) * 8;
    const unsigned short* pa0 = A + (size_t)(tm * 64 + srow) * K + scol;
    const unsigned short* pb0 = Bt + (size_t)(tn * 128 + srow) * K + scol;
    const unsigned short* pb1 = Bt + (size_t)(tn * 128 + srow + 64) * K + scol;

    floatx4 acc[4][2];
    #pragma unroll
    for (int i = 0; i < 4; ++i)
        #pragma unroll
        for (int j = 0; j < 2; ++j)
            acc[i][j] = (floatx4){0.0f, 0.0f, 0.0f, 0.0f};

    bf16x8 ra0 = *(const bf16x8*)pa0;
    bf16x8 rb0 = *(const bf16x8*)pb0;
    bf16x8 rb1 = *(const bf16x8*)pb1;

    for (int k0 = 0; k0 < K; k0 += BK) {
        *(bf16x8*)&As[srow][scol]      = ra0;
        *(bf16x8*)&Bs[srow][scol]      = rb0;
        *(bf16x8*)&Bs[srow + 64][scol] = rb1;
        __syncthreads();
        if (k0 + BK < K) {
            ra0 = *(const bf16x8*)(pa0 + k0 + BK);
            rb0 = *(const bf16x8*)(pb0 + k0 + BK);
            rb1 = *(const bf16x8*)(pb1 + k0 + BK);
        }
        bf16x8 af[4], bfr[2];
        #pragma unroll
        for (int i = 0; i < 4; ++i)
            af[i] = *(const bf16x8*)&As[i * 16 + r16][quad * 8];
        #pragma unroll
        for (int j = 0; j < 2; ++j)
            bfr[j] = *(const bf16x8*)&Bs[wave * 32 + j * 16 + r16][quad * 8];
        #pragma unroll
        for (int i = 0; i < 4; ++i)
            #pragma unroll
            for (int j = 0; j < 2; ++j)
                acc[i][j] = __builtin_amdgcn_mfma_f32_16x16x32_bf16(af[i], bfr[j], acc[i][j], 0, 0, 0);
        __syncthreads();
    }

    #pragma unroll
    for (int j = 0; j < 2; ++j) {
        int ocol = tn * 128 + wave * 32 + j * 16 + r16;
        float bv = bias[ocol];
        #pragma unroll
        for (int i = 0; i < 4; ++i) {
            int orow = tm * 64 + i * 16 + quad * 4;
            #pragma unroll
            for (int r = 0; r < 4; ++r) {
                float v = acc[i][j][r] + bv;
                if (mode == 1 && v < 0.0f) v = 0.0f;
                outb[(size_t)(orow + r) * N + ocol] = f2b(v);
            }
        }
    }
}

__device__ __forceinline__ void gemm128_gather_tile(int tm, int tn,
    const unsigned short* __restrict__ h_node, const int* __restrict__ agent,
    const int* __restrict__ nid, const unsigned short* __restrict__ Bt,
    const float* __restrict__ bias, unsigned short* __restrict__ outb,
    int N, int K,
    unsigned short (*As)[LDK], unsigned short (*Bs)[LDK]) {
    int tid = threadIdx.x;
    int lane = tid & 63, wave = tid >> 6;
    int wm = wave >> 1, wn = wave & 1;
    int r16 = lane & 15, quad = lane >> 4;
    int srow = tid >> 2, scol = (tid & 3) * 8;
    int c0 = nid[agent[tm * 128 + srow]];
    int c1 = nid[agent[tm * 128 + srow + 64]];
    const unsigned short* pa0 = h_node + (size_t)c0 * K + scol;
    const unsigned short* pa1 = h_node + (size_t)c1 * K + scol;
    const unsigned short* pb0 = Bt + (size_t)(tn * 128 + srow) * K + scol;
    const unsigned short* pb1 = Bt + (size_t)(tn * 128 + srow + 64) * K + scol;

    floatx4 acc[4][4];
    #pragma unroll
    for (int i = 0; i < 4; ++i)
        #pragma unroll
        for (int j = 0; j < 4; ++j)
            acc[i][j] = (floatx4){0.0f, 0.0f, 0.0f, 0.0f};

    bf16x8 ra0 = *(const bf16x8*)pa0;
    bf16x8 ra1 = *(const bf16x8*)pa1;
    bf16x8 rb0 = *(const bf16x8*)pb0;
    bf16x8 rb1 = *(const bf16x8*)pb1;

    for (int k0 = 0; k0 < K; k0 += BK) {
        *(bf16x8*)&As[srow][scol]      = ra0;
        *(bf16x8*)&As[srow + 64][scol] = ra1;
        *(bf16x8*)&Bs[srow][scol]      = rb0;
        *(bf16x8*)&Bs[srow + 64][scol] = rb1;
        __syncthreads();
        if (k0 + BK < K) {
            ra0 = *(const bf16x8*)(pa0 + k0 + BK);
            ra1 = *(const bf16x8*)(pa1 + k0 + BK);
            rb0 = *(const bf16x8*)(pb0 + k0 + BK);
            rb1 = *(const bf16x8*)(pb1 + k0 + BK);
        }
        bf16x8 af[4], bfr[4];
        #pragma unroll
        for (int i = 0; i < 4; ++i)
            af[i] = *(const bf16x8*)&As[wm * 64 + i * 16 + r16][quad * 8];
        #pragma unroll
        for (int j = 0; j < 4; ++j)
            bfr[j] = *(const bf16x8*)&Bs[wn * 64 + j * 16 + r16][quad * 8];
        #pragma unroll
        for (int i = 0; i < 4; ++i)
            #pragma unroll
            for (int j = 0; j < 4; ++j)
                acc[i][j] = __builtin_amdgcn_mfma_f32_16x16x32_bf16(af[i], bfr[j], acc[i][j], 0, 0, 0);
        __syncthreads();
    }

    #pragma unroll
    for (int j = 0; j < 4; ++j) {
        int ocol = tn * 128 + wn * 64 + j * 16 + r16;
        float bv = bias[ocol];
        #pragma unroll
        for (int i = 0; i < 4; ++i) {
            int orow = tm * 128 + wm * 64 + i * 16 + quad * 4;
            #pragma unroll
            for (int r = 0; r < 4; ++r)
                outb[(size_t)(orow + r) * N + ocol] = f2b(acc[i][j][r] + bv);
        }
    }
}

__device__ __forceinline__ void wtr_block(int b, int tid,
    const float* __restrict__ Wgcn, const float* __restrict__ W1,
    const float* __restrict__ W2, const float* __restrict__ Wmu,
    unsigned short* __restrict__ wgcn_t, unsigned short* __restrict__ w1_t,
    unsigned short* __restrict__ w2_t, unsigned short* __restrict__ wmu_t,
    unsigned short (*Ts)[72]) {
    const float* src; unsigned short* dstw; int K, N, tk, tn;
    if (b < 8)        { src = Wgcn; dstw = wgcn_t; K = IN_DIM; N = HID;  tk = b >> 2;        tn = b & 3; }
    else if (b < 72)  { int bb = b - 8;  src = W1; dstw = w1_t; K = HID;  N = FC1;  tk = bb >> 4; tn = bb & 15; }
    else if (b < 200) { int bb = b - 72; src = W2; dstw = w2_t; K = FC1;  N = FC2;  tk = bb >> 3; tn = bb & 7; }
    else              { int bb = b - 200; src = Wmu; dstw = wmu_t; K = FC2; N = N_ACT; tk = bb;   tn = 0; }
    int k0 = tk * 64, n0 = tn * 64;
    int r = tid >> 2;
    int cc = (tid & 3) * 16;
    if (n0 + cc < N) {
        const float* p = src + (size_t)(k0 + r) * N + n0 + cc;
        #pragma unroll
        for (int i = 0; i < 16; i += 4) {
            float4 v = *(const float4*)(p + i);
            Ts[r][cc + i + 0] = f2b(v.x);
            Ts[r][cc + i + 1] = f2b(v.y);
            Ts[r][cc + i + 2] = f2b(v.z);
            Ts[r][cc + i + 3] = f2b(v.w);
        }
    }
    __syncthreads();
    int n = tid >> 2;
    if (n0 + n < N) {
        bf16x8 o0, o1;
        #pragma unroll
        for (int i = 0; i < 8; ++i) o0[i] = (short)Ts[cc + i][n];
        #pragma unroll
        for (int i = 0; i < 8; ++i) o1[i] = (short)Ts[cc + 8 + i][n];
        unsigned short* q = dstw + (size_t)(n0 + n) * K + k0 + cc;
        *(bf16x8*)q = o0;
        *(bf16x8*)(q + 8) = o1;
    }
}

// one shared buffer reused across mega phases (max member 20736 B)
union SMem {
    unsigned short ts[64][72];
    float part[4][IN_DIM];
    struct { unsigned short As[64][LDK];  unsigned short Bs[128][LDK]; } g64;
    struct { unsigned short As[128][LDK]; unsigned short Bs[128][LDK]; } g128;
    struct { unsigned short Hs[16][520];  float hred[4][64][4]; } lh;
    float red[8];
};

// ================= whole network as ONE cooperative kernel =================
__global__ __launch_bounds__(256, 2) void mega_k(
    const float* __restrict__ x,
    const int* __restrict__ srcp, const int* __restrict__ dstp,
    const int* __restrict__ agent,
    const float* __restrict__ Wgcn, const float* __restrict__ bgcn,
    const float* __restrict__ W1, const float* __restrict__ b1,
    const float* __restrict__ g1, const float* __restrict__ be1,
    const float* __restrict__ W2, const float* __restrict__ b2,
    const float* __restrict__ g2, const float* __restrict__ be2,
    const float* __restrict__ Wmu, const float* __restrict__ bmu,
    float* __restrict__ out,
    int* deg, int* nid, int* fill, int* cnt, int* etot,
    int* list, int* rowbeg, int* ebuf, float* dis,
    unsigned short* wgcn_t, unsigned short* w1_t, unsigned short* w2_t,
    unsigned short* wmu_t, unsigned short* agg, unsigned short* h_node,
    unsigned short* zb, unsigned short* h1) {
    cg::grid_group grid = cg::this_grid();
    __shared__ SMem sm;
    int tid = threadIdx.x;
    int bid = blockIdx.x;
    int gsz = gridDim.x;
    int gtid = bid * 256 + tid;
    int GSTRIDE = gsz * 256;

    // ---- P0: init workspace + weight transpose (first 208 blocks) ----
    for (int i = gtid; i < N_NODES; i += GSTRIDE) { deg[i] = 0; nid[i] = -1; }
    if (gtid < N_AGENTS) fill[gtid] = 0;
    if (gtid == 0) { *cnt = 0; *etot = 0; }
    if (bid < 208)
        wtr_block(bid, tid, Wgcn, W1, W2, Wmu, wgcn_t, w1_t, w2_t, wmu_t, sm.ts);
    grid.sync();

    // ---- P1: claim + degree ----
    for (int i = gtid; i < N_EDGES; i += GSTRIDE) atomicAdd(&deg[dstp[i]], 1);
    if (gtid < N_AGENTS) atomicCAS(&nid[agent[gtid]], -1, gtid);
    grid.sync();

    // ---- P2: compact + bump-alloc + dis ----
    for (int i = gtid; i < N_NODES; i += GSTRIDE) {
        int d = deg[i];
        dis[i] = rsqrtf((float)(d + 1));
        if (nid[i] != -1) {
            int c = atomicAdd(cnt, 1);
            nid[i] = c;
            list[c] = i;
            rowbeg[c] = atomicAdd(etot, d);
        }
    }
    grid.sync();

    // ---- P3: fill CSR ----
    for (int e = gtid; e < N_EDGES; e += GSTRIDE) {
        int c = nid[dstp[e]];
        if (c >= 0) {
            int p = atomicAdd(&fill[c], 1);
            ebuf[rowbeg[c] + p] = srcp[e];
        }
    }
    grid.sync();

    // ---- P4: aggregate raw x per needed node ----
    {
        int ncnt = *cnt;
        int lane = tid & 63, wave = tid >> 6;
        for (int c = bid; c < N_AGENTS; c += gsz) {
            if (c < ncnt) {
                int n = list[c];
                int beg = rowbeg[c], end = beg + deg[n];
                float dn = dis[n];
                float ax = 0.0f, ay = 0.0f;
                for (int i = beg + wave; i < end; i += 4) {
                    int s = ebuf[i];
                    float w = dis[s] * dn;
                    float2 u = *(const float2*)(x + (size_t)s * IN_DIM + lane * 2);
                    ax += w * u.x;
                    ay += w * u.y;
                }
                sm.part[wave][lane * 2 + 0] = ax;
                sm.part[wave][lane * 2 + 1] = ay;
                __syncthreads();
                if (tid < IN_DIM) {
                    float v = sm.part[0][tid] + sm.part[1][tid] + sm.part[2][tid] + sm.part[3][tid];
                    v += dn * dn * x[(size_t)n * IN_DIM + tid];
                    agg[(size_t)c * IN_DIM + tid] = f2b(v);
                }
                __syncthreads();
            }
        }
    }
    grid.sync();

    // ---- P5: GCN GEMM (256 tiles) ----
    for (int t = bid; t < (N_AGENTS / 64) * (HID / 128); t += gsz)
        gemm64_tile(t >> 1, t & 1, agg, wgcn_t, bgcn, h_node, HID, IN_DIM, 1,
                    sm.g64.As, sm.g64.Bs);
    grid.sync();

    // ---- P6: FC1 gather-GEMM (512 tiles) ----
    for (int t = bid; t < (N_AGENTS / 128) * (FC1 / 128); t += gsz)
        gemm128_gather_tile(t >> 3, t & 7, h_node, agent, nid, w1_t, b1, zb,
                            FC1, HID, sm.g128.As, sm.g128.Bs);
    grid.sync();

    // ---- P7: LN1 + ReLU ----
    {
        int wave = tid >> 6, lane = tid & 63;
        for (int row = bid; row < N_AGENTS; row += gsz) {
            size_t base = (size_t)row * FC1;
            float vreg[4];
            float s = 0.0f, s2 = 0.0f;
            #pragma unroll
            for (int i = 0; i < 4; ++i) {
                float v = b2f(zb[base + i * 256 + tid]);
                vreg[i] = v; s += v; s2 += v * v;
            }
            for (int off = 32; off > 0; off >>= 1) {
                s += __shfl_down(s, off);
                s2 += __shfl_down(s2, off);
            }
            if (lane == 0) { sm.red[wave] = s; sm.red[4 + wave] = s2; }
            __syncthreads();
            s  = sm.red[0] + sm.red[1] + sm.red[2] + sm.red[3];
            s2 = sm.red[4] + sm.red[5] + sm.red[6] + sm.red[7];
            float mean = s * (1.0f / FC1);
            float var = s2 * (1.0f / FC1) - mean * mean;
            float inv = rsqrtf(var + 1e-5f);
            #pragma unroll
            for (int i = 0; i < 4; ++i) {
                int c = i * 256 + tid;
                float v = (vreg[i] - mean) * inv * g1[c] + be1[c];
                if (v < 0.0f) v = 0.0f;
                h1[base + c] = f2b(v);
            }
            __syncthreads();
        }
    }
    grid.sync();

    // ---- P8: FC2 GEMM (512 tiles) ----
    for (int t = bid; t < (N_AGENTS / 64) * (FC2 / 128); t += gsz)
        gemm64_tile(t >> 2, t & 3, h1, w2_t, b2, zb, FC2, FC1, 0,
                    sm.g64.As, sm.g64.Bs);
    grid.sync();

    // ---- P9: LN2 + ReLU + head ----
    {
        int lane = tid & 63, wave = tid >> 6;
        int r16 = lane & 15, quad = lane >> 4;
        for (int gix = bid; gix < N_AGENTS / 16; gix += gsz) {
            {
                int row = tid >> 4;
                int sub = tid & 15;
                const unsigned short* src = zb + (size_t)(gix * 16 + row) * FC2 + sub * 32;
                bf16x8 a0 = *(const bf16x8*)(src);
                bf16x8 a1 = *(const bf16x8*)(src + 8);
                bf16x8 a2 = *(const bf16x8*)(src + 16);
                bf16x8 a3 = *(const bf16x8*)(src + 24);
                float v[32];
                #pragma unroll
                for (int i = 0; i < 8; ++i) {
                    v[i]      = b2f((unsigned short)a0[i]);
                    v[8 + i]  = b2f((unsigned short)a1[i]);
                    v[16 + i] = b2f((unsigned short)a2[i]);
                    v[24 + i] = b2f((unsigned short)a3[i]);
                }
                float s = 0.0f, s2 = 0.0f;
                #pragma unroll
                for (int i = 0; i < 32; ++i) { s += v[i]; s2 += v[i] * v[i]; }
                #pragma unroll
                for (int m = 1; m < 16; m <<= 1) {
                    s  += __shfl_xor(s, m);
                    s2 += __shfl_xor(s2, m);
                }
                float mean = s * (1.0f / FC2);
                float var = s2 * (1.0f / FC2) - mean * mean;
                float inv = rsqrtf(var + 1e-5f);
                #pragma unroll
                for (int i = 0; i < 32; ++i) {
                    int c = sub * 32 + i;
                    float w = (v[i] - mean) * inv * g2[c] + be2[c];
                    if (w < 0.0f) w = 0.0f;
                    sm.lh.Hs[row][c] = f2b(w);
                }
            }
            __syncthreads();
            floatx4 acc = {0.0f, 0.0f, 0.0f, 0.0f};
            #pragma unroll
            for (int st = 0; st < 4; ++st) {
                bf16x8 a = *(const bf16x8*)&sm.lh.Hs[r16][wave * 128 + st * 32 + quad * 8];
                bf16x8 b = *(const bf16x8*)(wmu_t + (size_t)r16 * FC2 + wave * 128 + st * 32 + quad * 8);
                acc = __builtin_amdgcn_mfma_f32_16x16x32_bf16(a, b, acc, 0, 0, 0);
            }
            #pragma unroll
            for (int r = 0; r < 4; ++r) sm.lh.hred[wave][lane][r] = acc[r];
            __syncthreads();
            if (wave == 0) {
                #pragma unroll
                for (int r = 0; r < 4; ++r) {
                    float v = sm.lh.hred[0][lane][r] + sm.lh.hred[1][lane][r]
                            + sm.lh.hred[2][lane][r] + sm.lh.hred[3][lane][r];
                    v += bmu[r16];
                    v = 1.0f / (1.0f + expf(-v));
                    out[(size_t)(gix * 16 + quad * 4 + r) * N_ACT + r16] = v;
                }
            }
            __syncthreads();
        }
    }
}

// ===================== fallback path (R13, proven 233.7 us) =====================

__global__ __launch_bounds__(256) void prep1w_k(const int* __restrict__ agent_idx,
                                                int* __restrict__ nid,
                                                const int* __restrict__ dst,
                                                int* __restrict__ deg,
                                                const float* __restrict__ Wgcn,
                                                const float* __restrict__ W1,
                                                const float* __restrict__ W2,
                                                const float* __restrict__ Wmu,
                                                unsigned short* __restrict__ wgcn_t,
                                                unsigned short* __restrict__ w1_t,
                                                unsigned short* __restrict__ w2_t,
                                                unsigned short* __restrict__ wmu_t) {
    __shared__ unsigned short Ts[64][72];
    if (blockIdx.x < PREP1_BLOCKS) {
        int i = blockIdx.x * 256 + threadIdx.x;
        if (i < N_AGENTS) atomicCAS(&nid[agent_idx[i]], -1, i);
        if (i < N_EDGES) atomicAdd(&deg[dst[i]], 1);
        return;
    }
    wtr_block(blockIdx.x - PREP1_BLOCKS, threadIdx.x, Wgcn, W1, W2, Wmu,
              wgcn_t, w1_t, w2_t, wmu_t, Ts);
}

__global__ __launch_bounds__(256) void prep2_k(int* __restrict__ nid,
                                               int* __restrict__ list,
                                               int* __restrict__ cnt,
                                               const int* __restrict__ deg,
                                               int* __restrict__ rowbeg,
                                               int* __restrict__ etot,
                                               float* __restrict__ dis) {
    int i = blockIdx.x * 256 + threadIdx.x;
    if (i < N_NODES) {
        int d = deg[i];
        dis[i] = rsqrtf((float)(d + 1));
        if (nid[i] != -1) {
            int c = atomicAdd(cnt, 1);
            nid[i] = c;
            list[c] = i;
            rowbeg[c] = atomicAdd(etot, d);
        }
    }
}

__global__ __launch_bounds__(256) void fill_k(const int* __restrict__ src,
                                              const int* __restrict__ dst,
                                              const int* __restrict__ nid,
                                              const int* __restrict__ rowbeg,
                                              int* __restrict__ fill,
                                              int* __restrict__ ebuf) {
    int e = blockIdx.x * 256 + threadIdx.x;
    if (e >= N_EDGES) return;
    int c = nid[dst[e]];
    if (c < 0) return;
    int p = atomicAdd(&fill[c], 1);
    ebuf[rowbeg[c] + p] = src[e];
}

__global__ __launch_bounds__(256) void accumx_k(const int* __restrict__ cntp,
                                                const int* __restrict__ list,
                                                const int* __restrict__ rowbeg,
                                                const int* __restrict__ deg,
                                                const int* __restrict__ ebuf,
                                                const float* __restrict__ dis,
                                                const float* __restrict__ x,
                                                unsigned short* __restrict__ agg) {
    int c = blockIdx.x;
    if (c >= *cntp) return;
    int n = list[c];
    int lane = threadIdx.x & 63;
    int wave = threadIdx.x >> 6;
    int beg = rowbeg[c];
    int end = beg + deg[n];
    float dn = dis[n];
    float ax = 0.0f, ay = 0.0f;
    for (int i = beg + wave; i < end; i += 4) {
        int s = ebuf[i];
        float w = dis[s] * dn;
        float2 u = *(const float2*)(x + (size_t)s * IN_DIM + lane * 2);
        ax += w * u.x;
        ay += w * u.y;
    }
    __shared__ float part[4][IN_DIM];
    part[wave][lane * 2 + 0] = ax;
    part[wave][lane * 2 + 1] = ay;
    __syncthreads();
    int t = threadIdx.x;
    if (t < IN_DIM) {
        float v = part[0][t] + part[1][t] + part[2][t] + part[3][t];
        v += dn * dn * x[(size_t)n * IN_DIM + t];
        agg[(size_t)c * IN_DIM + t] = f2b(v);
    }
}

__global__ __launch_bounds__(256) void gemm_tiled64_k(const unsigned short* __restrict__ A,
                                                      const unsigned short* __restrict__ Bt,
                                                      const float* __restrict__ bias,
                                                      unsigned short* __restrict__ outb,
                                                      int N, int K, int mode) {
    __shared__ unsigned short As[64][LDK];
    __shared__ unsigned short Bs[128][LDK];
    gemm64_tile(blockIdx.y, blockIdx.x, A, Bt, bias, outb, N, K, mode, As, Bs);
}

__global__ __launch_bounds__(256) void gemm_tiled_gather_k(const unsigned short* __restrict__ h_node,
                                                           const int* __restrict__ agent,
                                                           const int* __restrict__ nid,
                                                           const unsigned short* __restrict__ Bt,
                                                           const float* __restrict__ bias,
                                                           unsigned short* __restrict__ outb,
                                                           int N, int K) {
    __shared__ unsigned short As[BM][LDK];
    __shared__ unsigned short Bs[BN][LDK];
    gemm128_gather_tile(blockIdx.y, blockIdx.x, h_node, agent, nid, Bt, bias, outb,
                        N, K, As, Bs);
}

__global__ __launch_bounds__(256) void ln_relu_k(const unsigned short* __restrict__ z,
                                                 const float* __restrict__ g,
                                                 const float* __restrict__ be,
                                                 unsigned short* __restrict__ out, int L) {
    size_t base = (size_t)blockIdx.x * L;
    int nc = L >> 8;
    float vreg[4];
    float s = 0.0f, s2 = 0.0f;
    for (int i = 0; i < nc; ++i) {
        float v = b2f(z[base + i * 256 + threadIdx.x]);
        vreg[i] = v;
        s += v;
        s2 += v * v;
    }
    for (int off = 32; off > 0; off >>= 1) {
        s += __shfl_down(s, off);
        s2 += __shfl_down(s2, off);
    }
    __shared__ float red[8];
    int wave = threadIdx.x >> 6;
    int lane = threadIdx.x & 63;
    if (lane == 0) { red[wave] = s; red[4 + wave] = s2; }
    __syncthreads();
    s  = red[0] + red[1] + red[2] + red[3];
    s2 = red[4] + red[5] + red[6] + red[7];
    float invL = 1.0f / (float)L;
    float mean = s * invL;
    float var = s2 * invL - mean * mean;
    float inv = rsqrtf(var + 1e-5f);
    for (int i = 0; i < nc; ++i) {
        int c = i * 256 + threadIdx.x;
        float v = (vreg[i] - mean) * inv * g[c] + be[c];
        if (v < 0.0f) v = 0.0f;
        out[base + c] = f2b(v);
    }
}

__global__ __launch_bounds__(256) void ln2head_k(const unsigned short* __restrict__ z,
                                                 const float* __restrict__ g2,
                                                 const float* __restrict__ be2,
                                                 const unsigned short* __restrict__ wmu_t,
                                                 const float* __restrict__ bmu,
                                                 float* __restrict__ out) {
    __shared__ unsigned short Hs[16][520];
    __shared__ float hred[4][64][4];
    int tid = threadIdx.x;
    int tm = blockIdx.x;
    {
        int row = tid >> 4;
        int sub = tid & 15;
        const unsigned short* src = z + (size_t)(tm * 16 + row) * FC2 + sub * 32;
        bf16x8 a0 = *(const bf16x8*)(src);
        bf16x8 a1 = *(const bf16x8*)(src + 8);
        bf16x8 a2 = *(const bf16x8*)(src + 16);
        bf16x8 a3 = *(const bf16x8*)(src + 24);
        float v[32];
        #pragma unroll
        for (int i = 0; i < 8; ++i) {
            v[i]      = b2f((unsigned short)a0[i]);
            v[8 + i]  = b2f((unsigned short)a1[i]);
            v[16 + i] = b2f((unsigned short)a2[i]);
            v[24 + i] = b2f((unsigned short)a3[i]);
        }
        float s = 0.0f, s2 = 0.0f;
        #pragma unroll
        for (int i = 0; i < 32; ++i) { s += v[i]; s2 += v[i] * v[i]; }
        #pragma unroll
        for (int m = 1; m < 16; m <<= 1) {
            s  += __shfl_xor(s, m);
            s2 += __shfl_xor(s2, m);
        }
        float mean = s * (1.0f / FC2);
        float var = s2 * (1.0f / FC2) - mean * mean;
        float inv = rsqrtf(var + 1e-5f);
        #pragma unroll
        for (int i = 0; i < 32; ++i) {
            int c = sub * 32 + i;
            float w = (v[i] - mean) * inv * g2[c] + be2[c];
            if (w < 0.0f) w = 0.0f;
            Hs[row][c] = f2b(w);
        }
    }
    __syncthreads();
    int lane = tid & 63, wave = tid >> 6;
    int r16 = lane & 15, quad = lane >> 4;
    floatx4 acc = {0.0f, 0.0f, 0.0f, 0.0f};
    #pragma unroll
    for (int st = 0; st < 4; ++st) {
        bf16x8 a = *(const bf16x8*)&Hs[r16][wave * 128 + st * 32 + quad * 8];
        bf16x8 b = *(const bf16x8*)(wmu_t + (size_t)r16 * FC2 + wave * 128 + st * 32 + quad * 8);
        acc = __builtin_amdgcn_mfma_f32_16x16x32_bf16(a, b, acc, 0, 0, 0);
    }
    #pragma unroll
    for (int r = 0; r < 4; ++r) hred[wave][lane][r] = acc[r];
    __syncthreads();
    if (wave == 0) {
        #pragma unroll
        for (int r = 0; r < 4; ++r) {
            float v = hred[0][lane][r] + hred[1][lane][r] + hred[2][lane][r] + hred[3][lane][r];
            v += bmu[r16];
            v = 1.0f / (1.0f + expf(-v));
            out[(size_t)(tm * 16 + quad * 4 + r) * N_ACT + r16] = v;
        }
    }
}

extern "C" void kernel_launch(void* const* d_in, const int* in_sizes, int n_in,
                              void* d_out, int out_size, void* d_ws, size_t ws_size,
                              hipStream_t stream) {
    const float* x    = (const float*)d_in[0];
    const int*   ei   = (const int*)d_in[1];
    const int*   agent= (const int*)d_in[2];
    const float* Wgcn = (const float*)d_in[3];
    const float* bgcn = (const float*)d_in[4];
    const float* W1   = (const float*)d_in[5];
    const float* b1   = (const float*)d_in[6];
    const float* g1   = (const float*)d_in[7];
    const float* be1  = (const float*)d_in[8];
    const float* W2   = (const float*)d_in[9];
    const float* b2   = (const float*)d_in[10];
    const float* g2   = (const float*)d_in[11];
    const float* be2  = (const float*)d_in[12];
    const float* Wmu  = (const float*)d_in[13];
    const float* bmu  = (const float*)d_in[14];
    float* out = (float*)d_out;

    const int* srcp = ei;
    const int* dstp = ei + N_EDGES;

    // workspace layout (256B aligned). Zero region contiguous: deg|fill|cnt|etot.
    char* ws = (char*)d_ws;
    size_t off = 0;
    char* zero_base = ws;
    int* deg = (int*)(ws + off);     off += ((size_t)N_NODES * 4 + 255) & ~(size_t)255;
    int* fill = (int*)(ws + off);    off += ((size_t)N_AGENTS * 4 + 255) & ~(size_t)255;
    int* cnt = (int*)(ws + off);     off += 256;
    int* etot = (int*)(ws + off);    off += 256;
    size_t zero_bytes = off;
    int* nid = (int*)(ws + off);     off += ((size_t)N_NODES * 4 + 255) & ~(size_t)255;
    float* dis = (float*)(ws + off); off += ((size_t)N_NODES * 4 + 255) & ~(size_t)255;
    int* list = (int*)(ws + off);    off += ((size_t)N_AGENTS * 4 + 255) & ~(size_t)255;
    int* rowbeg = (int*)(ws + off);  off += ((size_t)N_AGENTS * 4 + 255) & ~(size_t)255;
    int* ebuf = (int*)(ws + off);    off += ((size_t)N_EDGES * 4 + 255) & ~(size_t)255;
    unsigned short* wgcn_t = (unsigned short*)(ws + off); off += ((size_t)IN_DIM * HID * 2 + 255) & ~(size_t)255;
    unsigned short* w1_t   = (unsigned short*)(ws + off); off += ((size_t)HID * FC1 * 2 + 255) & ~(size_t)255;
    unsigned short* w2_t   = (unsigned short*)(ws + off); off += ((size_t)FC1 * FC2 * 2 + 255) & ~(size_t)255;
    unsigned short* wmu_t  = (unsigned short*)(ws + off); off += ((size_t)FC2 * N_ACT * 2 + 255) & ~(size_t)255;
    unsigned short* agg    = (unsigned short*)(ws + off); off += ((size_t)N_AGENTS * IN_DIM * 2 + 255) & ~(size_t)255;
    unsigned short* h_node = (unsigned short*)(ws + off); off += ((size_t)N_AGENTS * HID * 2 + 255) & ~(size_t)255;
    unsigned short* zb = (unsigned short*)(ws + off);     off += ((size_t)N_AGENTS * FC1 * 2 + 255) & ~(size_t)255;
    unsigned short* h1 = (unsigned short*)(ws + off);     off += ((size_t)N_AGENTS * FC1 * 2 + 255) & ~(size_t)255;

    // ---- attempt cooperative single-kernel path ----
    int occ = 0;
    hipError_t oerr = hipOccupancyMaxActiveBlocksPerMultiprocessor(
        &occ, (const void*)mega_k, 256, 0);
    bool coop_ok = false;
    if (oerr == hipSuccess && occ > 0) {
        int gsize = occ * 256;               // 256 CUs on MI355X
        if (gsize > 512) gsize = 512;
        if (gsize >= 256) {                  // need >= 208 for P0 transpose blocks
            void* kargs[] = {
                (void*)&x, (void*)&srcp, (void*)&dstp, (void*)&agent,
                (void*)&Wgcn, (void*)&bgcn, (void*)&W1, (void*)&b1,
                (void*)&g1, (void*)&be1, (void*)&W2, (void*)&b2,
                (void*)&g2, (void*)&be2, (void*)&Wmu, (void*)&bmu,
                (void*)&out,
                (void*)&deg, (void*)&nid, (void*)&fill, (void*)&cnt, (void*)&etot,
                (void*)&list, (void*)&rowbeg, (void*)&ebuf, (void*)&dis,
                (void*)&wgcn_t, (void*)&w1_t, (void*)&w2_t, (void*)&wmu_t,
                (void*)&agg, (void*)&h_node, (void*)&zb, (void*)&h1
            };
            hipError_t lerr = hipLaunchCooperativeKernel((void*)mega_k, dim3(gsize),
                                                         dim3(256), kargs, 0, stream);
            coop_ok = (lerr == hipSuccess);
        }
    }
    if (coop_ok) return;

    // ---- fallback: proven R13 multi-kernel pipeline ----
    hipMemsetAsync(zero_base, 0, zero_bytes, stream);
    hipMemsetAsync(nid, 0xFF, (size_t)N_NODES * 4, stream);

    prep1w_k<<<PREP1_BLOCKS + WTR_BLOCKS, 256, 0, stream>>>(agent, nid, dstp, deg,
                                                            Wgcn, W1, W2, Wmu,
                                                            wgcn_t, w1_t, w2_t, wmu_t);
    prep2_k<<<(N_NODES + 255) / 256, 256, 0, stream>>>(nid, list, cnt, deg, rowbeg, etot, dis);
    fill_k<<<(N_EDGES + 255) / 256, 256, 0, stream>>>(srcp, dstp, nid, rowbeg, fill, ebuf);

    accumx_k<<<N_AGENTS, 256, 0, stream>>>(cnt, list, rowbeg, deg, ebuf, dis, x, agg);

    {
        dim3 grid(HID / 128, N_AGENTS / 64);
        gemm_tiled64_k<<<grid, 256, 0, stream>>>(agg, wgcn_t, bgcn, h_node, HID, IN_DIM, 1);
    }
    {
        dim3 grid(FC1 / BN, N_AGENTS / BM);
        gemm_tiled_gather_k<<<grid, 256, 0, stream>>>(h_node, agent, nid, w1_t, b1, zb,
                                                      FC1, HID);
        ln_relu_k<<<N_AGENTS, 256, 0, stream>>>(zb, g1, be1, h1, FC1);
    }
    {
        dim3 grid(FC2 / 128, N_AGENTS / 64);
        gemm_tiled64_k<<<grid, 256, 0, stream>>>(h1, w2_t, b2, zb, FC2, FC1, 0);
        ln2head_k<<<N_AGENTS / 16, 256, 0, stream>>>(zb, g2, be2, wmu_t, bmu, out);
    }
}

// Round 16
// 226.597 us; speedup vs baseline: 2.6870x; 2.6870x over previous
//
#include <hip/hip_runtime.h>
#include <hip/hip_bf16.h>
#include <math.h>

#define N_NODES  50000
#define N_EDGES  800000
#define IN_DIM   128
#define HID      256
#define FC1      1024
#define FC2      512
#define N_ACT    16
#define N_AGENTS 8192

#define BK       32
#define LDK      40
#define BM       128
#define BN       128

#define PREP1_BLOCKS ((N_EDGES + 255) / 256)    // 3125
#define WTR_BLOCKS   208

typedef short bf16x8 __attribute__((ext_vector_type(8)));
typedef float floatx4 __attribute__((ext_vector_type(4)));

__device__ __forceinline__ unsigned short f2b(float f) {
    union { float f; unsigned int i; } v;
    v.f = f;
    unsigned int lsb = (v.i >> 16) & 1u;
    v.i += 0x7fffu + lsb;            // round-to-nearest-even
    return (unsigned short)(v.i >> 16);
}

__device__ __forceinline__ float b2f(unsigned short u) {
    union { unsigned int i; float f; } v;
    v.i = ((unsigned int)u) << 16;
    return v.f;
}

// ---- weight transpose tile helper (f32 [K,N] -> bf16 [N,K], 64x64 via LDS) ----
__device__ __forceinline__ void wtr_block(int b, int tid,
    const float* __restrict__ Wgcn, const float* __restrict__ W1,
    const float* __restrict__ W2, const float* __restrict__ Wmu,
    unsigned short* __restrict__ wgcn_t, unsigned short* __restrict__ w1_t,
    unsigned short* __restrict__ w2_t, unsigned short* __restrict__ wmu_t,
    unsigned short (*Ts)[72]) {
    const float* src; unsigned short* dstw; int K, N, tk, tn;
    if (b < 8)        { src = Wgcn; dstw = wgcn_t; K = IN_DIM; N = HID;  tk = b >> 2;        tn = b & 3; }
    else if (b < 72)  { int bb = b - 8;  src = W1; dstw = w1_t; K = HID;  N = FC1;  tk = bb >> 4; tn = bb & 15; }
    else if (b < 200) { int bb = b - 72; src = W2; dstw = w2_t; K = FC1;  N = FC2;  tk = bb >> 3; tn = bb & 7; }
    else              { int bb = b - 200; src = Wmu; dstw = wmu_t; K = FC2; N = N_ACT; tk = bb;   tn = 0; }
    int k0 = tk * 64, n0 = tn * 64;
    int r = tid >> 2;
    int cc = (tid & 3) * 16;
    if (n0 + cc < N) {
        const float* p = src + (size_t)(k0 + r) * N + n0 + cc;
        #pragma unroll
        for (int i = 0; i < 16; i += 4) {
            float4 v = *(const float4*)(p + i);
            Ts[r][cc + i + 0] = f2b(v.x);
            Ts[r][cc + i + 1] = f2b(v.y);
            Ts[r][cc + i + 2] = f2b(v.z);
            Ts[r][cc + i + 3] = f2b(v.w);
        }
    }
    __syncthreads();
    int n = tid >> 2;
    if (n0 + n < N) {
        bf16x8 o0, o1;
        #pragma unroll
        for (int i = 0; i < 8; ++i) o0[i] = (short)Ts[cc + i][n];
        #pragma unroll
        for (int i = 0; i < 8; ++i) o1[i] = (short)Ts[cc + 8 + i][n];
        unsigned short* q = dstw + (size_t)(n0 + n) * K + k0 + cc;
        *(bf16x8*)q = o0;
        *(bf16x8*)(q + 8) = o1;
    }
}

// ---- fused: claim (nid: 0=free, i+1=claimed) + degree; tail blocks: transpose ----
__global__ __launch_bounds__(256) void prep1w_k(const int* __restrict__ agent_idx,
                                                int* __restrict__ nid,
                                                const int* __restrict__ dst,
                                                int* __restrict__ deg,
                                                const float* __restrict__ Wgcn,
                                                const float* __restrict__ W1,
                                                const float* __restrict__ W2,
                                                const float* __restrict__ Wmu,
                                                unsigned short* __restrict__ wgcn_t,
                                                unsigned short* __restrict__ w1_t,
                                                unsigned short* __restrict__ w2_t,
                                                unsigned short* __restrict__ wmu_t) {
    __shared__ unsigned short Ts[64][72];
    if (blockIdx.x < PREP1_BLOCKS) {
        int i = blockIdx.x * 256 + threadIdx.x;
        if (i < N_AGENTS) atomicCAS(&nid[agent_idx[i]], 0, i + 1);
        if (i < N_EDGES) atomicAdd(&deg[dst[i]], 1);
        return;
    }
    wtr_block(blockIdx.x - PREP1_BLOCKS, threadIdx.x, Wgcn, W1, W2, Wmu,
              wgcn_t, w1_t, w2_t, wmu_t, Ts);
}

// ---- compact (nid -> c+1) + bump-alloc row bases + dis ----
__global__ __launch_bounds__(256) void prep2_k(int* __restrict__ nid,
                                               int* __restrict__ list,
                                               int* __restrict__ cnt,
                                               const int* __restrict__ deg,
                                               int* __restrict__ rowbeg,
                                               int* __restrict__ etot,
                                               float* __restrict__ dis) {
    int i = blockIdx.x * 256 + threadIdx.x;
    if (i < N_NODES) {
        int d = deg[i];
        dis[i] = rsqrtf((float)(d + 1));
        if (nid[i] != 0) {
            int c = atomicAdd(cnt, 1);
            nid[i] = c + 1;
            list[c] = i;
            rowbeg[c] = atomicAdd(etot, d);
        }
    }
}

// ---- fill CSR buckets ----
__global__ __launch_bounds__(256) void fill_k(const int* __restrict__ src,
                                              const int* __restrict__ dst,
                                              const int* __restrict__ nid,
                                              const int* __restrict__ rowbeg,
                                              int* __restrict__ fill,
                                              int* __restrict__ ebuf) {
    int e = blockIdx.x * 256 + threadIdx.x;
    if (e >= N_EDGES) return;
    int cc = nid[dst[e]];
    if (cc == 0) return;
    int c = cc - 1;
    int p = atomicAdd(&fill[c], 1);
    ebuf[rowbeg[c] + p] = src[e];
}

// ---- aggregate raw x per needed node -> agg bf16 [c][128] ----
__global__ __launch_bounds__(256) void accumx_k(const int* __restrict__ cntp,
                                                const int* __restrict__ list,
                                                const int* __restrict__ rowbeg,
                                                const int* __restrict__ deg,
                                                const int* __restrict__ ebuf,
                                                const float* __restrict__ dis,
                                                const float* __restrict__ x,
                                                unsigned short* __restrict__ agg) {
    int c = blockIdx.x;
    if (c >= *cntp) return;
    int n = list[c];
    int lane = threadIdx.x & 63;
    int wave = threadIdx.x >> 6;
    int beg = rowbeg[c];
    int end = beg + deg[n];
    float dn = dis[n];
    float ax = 0.0f, ay = 0.0f;
    for (int i = beg + wave; i < end; i += 4) {
        int s = ebuf[i];
        float w = dis[s] * dn;
        float2 u = *(const float2*)(x + (size_t)s * IN_DIM + lane * 2);
        ax += w * u.x;
        ay += w * u.y;
    }
    __shared__ float part[4][IN_DIM];
    part[wave][lane * 2 + 0] = ax;
    part[wave][lane * 2 + 1] = ay;
    __syncthreads();
    int t = threadIdx.x;
    if (t < IN_DIM) {
        float v = part[0][t] + part[1][t] + part[2][t] + part[3][t];
        v += dn * dn * x[(size_t)n * IN_DIM + t];
        agg[(size_t)c * IN_DIM + t] = f2b(v);
    }
}

// ---- GCN GEMM: 64x128 tile, bf16(relu(v+bias)) out ----
__global__ __launch_bounds__(256) void gemm_gcn_k(const unsigned short* __restrict__ A,
                                                  const unsigned short* __restrict__ Bt,
                                                  const float* __restrict__ bias,
                                                  unsigned short* __restrict__ outb) {
    __shared__ unsigned short As[64][LDK];
    __shared__ unsigned short Bs[128][LDK];
    int tn = blockIdx.x, tm = blockIdx.y;
    int tid = threadIdx.x;
    int lane = tid & 63, wave = tid >> 6;
    int r16 = lane & 15, quad = lane >> 4;
    int srow = tid >> 2, scol = (tid & 3) * 8;
    const int K = IN_DIM, N = HID;
    const unsigned short* pa0 = A + (size_t)(tm * 64 + srow) * K + scol;
    const unsigned short* pb0 = Bt + (size_t)(tn * 128 + srow) * K + scol;
    const unsigned short* pb1 = Bt + (size_t)(tn * 128 + srow + 64) * K + scol;

    floatx4 acc[4][2];
    #pragma unroll
    for (int i = 0; i < 4; ++i)
        #pragma unroll
        for (int j = 0; j < 2; ++j)
            acc[i][j] = (floatx4){0.0f, 0.0f, 0.0f, 0.0f};

    bf16x8 ra0 = *(const bf16x8*)pa0;
    bf16x8 rb0 = *(const bf16x8*)pb0;
    bf16x8 rb1 = *(const bf16x8*)pb1;

    for (int k0 = 0; k0 < K; k0 += BK) {
        *(bf16x8*)&As[srow][scol]      = ra0;
        *(bf16x8*)&Bs[srow][scol]      = rb0;
        *(bf16x8*)&Bs[srow + 64][scol] = rb1;
        __syncthreads();
        if (k0 + BK < K) {
            ra0 = *(const bf16x8*)(pa0 + k0 + BK);
            rb0 = *(const bf16x8*)(pb0 + k0 + BK);
            rb1 = *(const bf16x8*)(pb1 + k0 + BK);
        }
        bf16x8 af[4], bfr[2];
        #pragma unroll
        for (int i = 0; i < 4; ++i)
            af[i] = *(const bf16x8*)&As[i * 16 + r16][quad * 8];
        #pragma unroll
        for (int j = 0; j < 2; ++j)
            bfr[j] = *(const bf16x8*)&Bs[wave * 32 + j * 16 + r16][quad * 8];
        #pragma unroll
        for (int i = 0; i < 4; ++i)
            #pragma unroll
            for (int j = 0; j < 2; ++j)
                acc[i][j] = __builtin_amdgcn_mfma_f32_16x16x32_bf16(af[i], bfr[j], acc[i][j], 0, 0, 0);
        __syncthreads();
    }

    #pragma unroll
    for (int j = 0; j < 2; ++j) {
        int ocol = tn * 128 + wave * 32 + j * 16 + r16;
        float bv = bias[ocol];
        #pragma unroll
        for (int i = 0; i < 4; ++i) {
            int orow = tm * 64 + i * 16 + quad * 4;
            #pragma unroll
            for (int r = 0; r < 4; ++r) {
                float v = acc[i][j][r] + bv;
                if (v < 0.0f) v = 0.0f;
                outb[(size_t)(orow + r) * N + ocol] = f2b(v);
            }
        }
    }
}

// ---- FC1: 128x128 gather GEMM + bias, writes zb AND per-row LN stats (atomics) ----
__global__ __launch_bounds__(256) void gemm_fc1_k(const unsigned short* __restrict__ h_node,
                                                  const int* __restrict__ agent,
                                                  const int* __restrict__ nid,
                                                  const unsigned short* __restrict__ Bt,
                                                  const float* __restrict__ bias,
                                                  unsigned short* __restrict__ outb,
                                                  float* __restrict__ rowsum,
                                                  float* __restrict__ rowsumsq) {
    __shared__ unsigned short As[BM][LDK];
    __shared__ unsigned short Bs[BN][LDK];
    int tn = blockIdx.x, tm = blockIdx.y;
    int tid = threadIdx.x;
    int lane = tid & 63, wave = tid >> 6;
    int wm = wave >> 1, wn = wave & 1;
    int r16 = lane & 15, quad = lane >> 4;
    int srow = tid >> 2, scol = (tid & 3) * 8;
    const int K = HID, N = FC1;
    int c0 = nid[agent[tm * BM + srow]] - 1;
    int c1 = nid[agent[tm * BM + srow + 64]] - 1;
    const unsigned short* pa0 = h_node + (size_t)c0 * K + scol;
    const unsigned short* pa1 = h_node + (size_t)c1 * K + scol;
    const unsigned short* pb0 = Bt + (size_t)(tn * BN + srow) * K + scol;
    const unsigned short* pb1 = Bt + (size_t)(tn * BN + srow + 64) * K + scol;

    floatx4 acc[4][4];
    #pragma unroll
    for (int i = 0; i < 4; ++i)
        #pragma unroll
        for (int j = 0; j < 4; ++j)
            acc[i][j] = (floatx4){0.0f, 0.0f, 0.0f, 0.0f};

    bf16x8 ra0 = *(const bf16x8*)pa0;
    bf16x8 ra1 = *(const bf16x8*)pa1;
    bf16x8 rb0 = *(const bf16x8*)pb0;
    bf16x8 rb1 = *(const bf16x8*)pb1;

    for (int k0 = 0; k0 < K; k0 += BK) {
        *(bf16x8*)&As[srow][scol]      = ra0;
        *(bf16x8*)&As[srow + 64][scol] = ra1;
        *(bf16x8*)&Bs[srow][scol]      = rb0;
        *(bf16x8*)&Bs[srow + 64][scol] = rb1;
        __syncthreads();
        if (k0 + BK < K) {
            ra0 = *(const bf16x8*)(pa0 + k0 + BK);
            ra1 = *(const bf16x8*)(pa1 + k0 + BK);
            rb0 = *(const bf16x8*)(pb0 + k0 + BK);
            rb1 = *(const bf16x8*)(pb1 + k0 + BK);
        }
        bf16x8 af[4], bfr[4];
        #pragma unroll
        for (int i = 0; i < 4; ++i)
            af[i] = *(const bf16x8*)&As[wm * 64 + i * 16 + r16][quad * 8];
        #pragma unroll
        for (int j = 0; j < 4; ++j)
            bfr[j] = *(const bf16x8*)&Bs[wn * 64 + j * 16 + r16][quad * 8];
        #pragma unroll
        for (int i = 0; i < 4; ++i)
            #pragma unroll
            for (int j = 0; j < 4; ++j)
                acc[i][j] = __builtin_amdgcn_mfma_f32_16x16x32_bf16(af[i], bfr[j], acc[i][j], 0, 0, 0);
        __syncthreads();
    }

    float bvj[4];
    #pragma unroll
    for (int j = 0; j < 4; ++j) bvj[j] = bias[tn * BN + wn * 64 + j * 16 + r16];

    #pragma unroll
    for (int i = 0; i < 4; ++i) {
        #pragma unroll
        for (int r = 0; r < 4; ++r) {
            int orow = tm * BM + wm * 64 + i * 16 + quad * 4 + r;
            float vs = 0.0f, vs2 = 0.0f;
            #pragma unroll
            for (int j = 0; j < 4; ++j) {
                int ocol = tn * BN + wn * 64 + j * 16 + r16;
                float v = acc[i][j][r] + bvj[j];
                outb[(size_t)orow * N + ocol] = f2b(v);
                vs += v;
                vs2 += v * v;
            }
            // reduce across the 16 lanes sharing this row (masks < 16 stay in-group)
            #pragma unroll
            for (int m = 1; m < 16; m <<= 1) {
                vs  += __shfl_xor(vs, m);
                vs2 += __shfl_xor(vs2, m);
            }
            if (r16 == 0) {
                atomicAdd(&rowsum[orow], vs);
                atomicAdd(&rowsumsq[orow], vs2);
            }
        }
    }
}

// ---- FC2: 64x128 GEMM whose A-staging applies LN1+affine+ReLU on the fly ----
__global__ __launch_bounds__(256) void gemm_fc2ln_k(const unsigned short* __restrict__ zb,
                                                    const float* __restrict__ rowsum,
                                                    const float* __restrict__ rowsumsq,
                                                    const float* __restrict__ g1,
                                                    const float* __restrict__ be1,
                                                    const unsigned short* __restrict__ Bt,
                                                    const float* __restrict__ bias,
                                                    unsigned short* __restrict__ outb) {
    __shared__ unsigned short As[64][LDK];
    __shared__ unsigned short Bs[128][LDK];
    int tn = blockIdx.x, tm = blockIdx.y;
    int tid = threadIdx.x;
    int lane = tid & 63, wave = tid >> 6;
    int r16 = lane & 15, quad = lane >> 4;
    int srow = tid >> 2, scol = (tid & 3) * 8;
    const int K = FC1, N = FC2;
    int arow = tm * 64 + srow;
    float s = rowsum[arow], s2 = rowsumsq[arow];
    float mean = s * (1.0f / FC1);
    float var = s2 * (1.0f / FC1) - mean * mean;
    float inv = rsqrtf(var + 1e-5f);
    const unsigned short* pa0 = zb + (size_t)arow * K + scol;
    const unsigned short* pb0 = Bt + (size_t)(tn * 128 + srow) * K + scol;
    const unsigned short* pb1 = Bt + (size_t)(tn * 128 + srow + 64) * K + scol;

    floatx4 acc[4][2];
    #pragma unroll
    for (int i = 0; i < 4; ++i)
        #pragma unroll
        for (int j = 0; j < 2; ++j)
            acc[i][j] = (floatx4){0.0f, 0.0f, 0.0f, 0.0f};

    bf16x8 ra0 = *(const bf16x8*)pa0;
    bf16x8 rb0 = *(const bf16x8*)pb0;
    bf16x8 rb1 = *(const bf16x8*)pb1;

    for (int k0 = 0; k0 < K; k0 += BK) {
        {   // LN + affine + relu during A staging
            bf16x8 ln;
            #pragma unroll
            for (int k = 0; k < 8; ++k) {
                int gk = k0 + scol + k;
                float v = (b2f((unsigned short)ra0[k]) - mean) * inv * g1[gk] + be1[gk];
                if (v < 0.0f) v = 0.0f;
                ln[k] = (short)f2b(v);
            }
            *(bf16x8*)&As[srow][scol] = ln;
        }
        *(bf16x8*)&Bs[srow][scol]      = rb0;
        *(bf16x8*)&Bs[srow + 64][scol] = rb1;
        __syncthreads();
        if (k0 + BK < K) {
            ra0 = *(const bf16x8*)(pa0 + k0 + BK);
            rb0 = *(const bf16x8*)(pb0 + k0 + BK);
            rb1 = *(const bf16x8*)(pb1 + k0 + BK);
        }
        bf16x8 af[4], bfr[2];
        #pragma unroll
        for (int i = 0; i < 4; ++i)
            af[i] = *(const bf16x8*)&As[i * 16 + r16][quad * 8];
        #pragma unroll
        for (int j = 0; j < 2; ++j)
            bfr[j] = *(const bf16x8*)&Bs[wave * 32 + j * 16 + r16][quad * 8];
        #pragma unroll
        for (int i = 0; i < 4; ++i)
            #pragma unroll
            for (int j = 0; j < 2; ++j)
                acc[i][j] = __builtin_amdgcn_mfma_f32_16x16x32_bf16(af[i], bfr[j], acc[i][j], 0, 0, 0);
        __syncthreads();
    }

    #pragma unroll
    for (int j = 0; j < 2; ++j) {
        int ocol = tn * 128 + wave * 32 + j * 16 + r16;
        float bv = bias[ocol];
        #pragma unroll
        for (int i = 0; i < 4; ++i) {
            int orow = tm * 64 + i * 16 + quad * 4;
            #pragma unroll
            for (int r = 0; r < 4; ++r)
                outb[(size_t)(orow + r) * N + ocol] = f2b(acc[i][j][r] + bv);
        }
    }
}

// ---- fused LN2 + ReLU + head, 16 rows/block (512 blocks) ----
__global__ __launch_bounds__(256) void ln2head_k(const unsigned short* __restrict__ z,
                                                 const float* __restrict__ g2,
                                                 const float* __restrict__ be2,
                                                 const unsigned short* __restrict__ wmu_t,
                                                 const float* __restrict__ bmu,
                                                 float* __restrict__ out) {
    __shared__ unsigned short Hs[16][520];
    __shared__ float hred[4][64][4];
    int tid = threadIdx.x;
    int tm = blockIdx.x;
    {
        int row = tid >> 4;
        int sub = tid & 15;
        const unsigned short* src = z + (size_t)(tm * 16 + row) * FC2 + sub * 32;
        bf16x8 a0 = *(const bf16x8*)(src);
        bf16x8 a1 = *(const bf16x8*)(src + 8);
        bf16x8 a2 = *(const bf16x8*)(src + 16);
        bf16x8 a3 = *(const bf16x8*)(src + 24);
        float v[32];
        #pragma unroll
        for (int i = 0; i < 8; ++i) {
            v[i]      = b2f((unsigned short)a0[i]);
            v[8 + i]  = b2f((unsigned short)a1[i]);
            v[16 + i] = b2f((unsigned short)a2[i]);
            v[24 + i] = b2f((unsigned short)a3[i]);
        }
        float s = 0.0f, s2 = 0.0f;
        #pragma unroll
        for (int i = 0; i < 32; ++i) { s += v[i]; s2 += v[i] * v[i]; }
        #pragma unroll
        for (int m = 1; m < 16; m <<= 1) {
            s  += __shfl_xor(s, m);
            s2 += __shfl_xor(s2, m);
        }
        float mean = s * (1.0f / FC2);
        float var = s2 * (1.0f / FC2) - mean * mean;
        float inv = rsqrtf(var + 1e-5f);
        #pragma unroll
        for (int i = 0; i < 32; ++i) {
            int c = sub * 32 + i;
            float w = (v[i] - mean) * inv * g2[c] + be2[c];
            if (w < 0.0f) w = 0.0f;
            Hs[row][c] = f2b(w);
        }
    }
    __syncthreads();
    int lane = tid & 63, wave = tid >> 6;
    int r16 = lane & 15, quad = lane >> 4;
    floatx4 acc = {0.0f, 0.0f, 0.0f, 0.0f};
    #pragma unroll
    for (int st = 0; st < 4; ++st) {
        bf16x8 a = *(const bf16x8*)&Hs[r16][wave * 128 + st * 32 + quad * 8];
        bf16x8 b = *(const bf16x8*)(wmu_t + (size_t)r16 * FC2 + wave * 128 + st * 32 + quad * 8);
        acc = __builtin_amdgcn_mfma_f32_16x16x32_bf16(a, b, acc, 0, 0, 0);
    }
    #pragma unroll
    for (int r = 0; r < 4; ++r) hred[wave][lane][r] = acc[r];
    __syncthreads();
    if (wave == 0) {
        #pragma unroll
        for (int r = 0; r < 4; ++r) {
            float v = hred[0][lane][r] + hred[1][lane][r] + hred[2][lane][r] + hred[3][lane][r];
            v += bmu[r16];
            v = 1.0f / (1.0f + expf(-v));
            out[(size_t)(tm * 16 + quad * 4 + r) * N_ACT + r16] = v;
        }
    }
}

extern "C" void kernel_launch(void* const* d_in, const int* in_sizes, int n_in,
                              void* d_out, int out_size, void* d_ws, size_t ws_size,
                              hipStream_t stream) {
    const float* x    = (const float*)d_in[0];
    const int*   ei   = (const int*)d_in[1];
    const int*   agent= (const int*)d_in[2];
    const float* Wgcn = (const float*)d_in[3];
    const float* bgcn = (const float*)d_in[4];
    const float* W1   = (const float*)d_in[5];
    const float* b1   = (const float*)d_in[6];
    const float* g1   = (const float*)d_in[7];
    const float* be1  = (const float*)d_in[8];
    const float* W2   = (const float*)d_in[9];
    const float* b2   = (const float*)d_in[10];
    const float* g2   = (const float*)d_in[11];
    const float* be2  = (const float*)d_in[12];
    const float* Wmu  = (const float*)d_in[13];
    const float* bmu  = (const float*)d_in[14];
    float* out = (float*)d_out;

    const int* srcp = ei;
    const int* dstp = ei + N_EDGES;

    // workspace layout (256B aligned). ONE contiguous zero region:
    // deg | fill | cnt | etot | rowsum | rowsumsq | nid   (nid: 0 = unclaimed)
    char* ws = (char*)d_ws;
    size_t off = 0;
    char* zero_base = ws;
    int* deg = (int*)(ws + off);       off += ((size_t)N_NODES * 4 + 255) & ~(size_t)255;
    int* fill = (int*)(ws + off);      off += ((size_t)N_AGENTS * 4 + 255) & ~(size_t)255;
    int* cnt = (int*)(ws + off);       off += 256;
    int* etot = (int*)(ws + off);      off += 256;
    float* rowsum = (float*)(ws + off);   off += ((size_t)N_AGENTS * 4 + 255) & ~(size_t)255;
    float* rowsumsq = (float*)(ws + off); off += ((size_t)N_AGENTS * 4 + 255) & ~(size_t)255;
    int* nid = (int*)(ws + off);       off += ((size_t)N_NODES * 4 + 255) & ~(size_t)255;
    size_t zero_bytes = off;
    float* dis = (float*)(ws + off);   off += ((size_t)N_NODES * 4 + 255) & ~(size_t)255;
    int* list = (int*)(ws + off);      off += ((size_t)N_AGENTS * 4 + 255) & ~(size_t)255;
    int* rowbeg = (int*)(ws + off);    off += ((size_t)N_AGENTS * 4 + 255) & ~(size_t)255;
    int* ebuf = (int*)(ws + off);      off += ((size_t)N_EDGES * 4 + 255) & ~(size_t)255;
    unsigned short* wgcn_t = (unsigned short*)(ws + off); off += ((size_t)IN_DIM * HID * 2 + 255) & ~(size_t)255;
    unsigned short* w1_t   = (unsigned short*)(ws + off); off += ((size_t)HID * FC1 * 2 + 255) & ~(size_t)255;
    unsigned short* w2_t   = (unsigned short*)(ws + off); off += ((size_t)FC1 * FC2 * 2 + 255) & ~(size_t)255;
    unsigned short* wmu_t  = (unsigned short*)(ws + off); off += ((size_t)FC2 * N_ACT * 2 + 255) & ~(size_t)255;
    unsigned short* agg    = (unsigned short*)(ws + off); off += ((size_t)N_AGENTS * IN_DIM * 2 + 255) & ~(size_t)255;
    unsigned short* h_node = (unsigned short*)(ws + off); off += ((size_t)N_AGENTS * HID * 2 + 255) & ~(size_t)255;
    unsigned short* zb  = (unsigned short*)(ws + off);    off += ((size_t)N_AGENTS * FC1 * 2 + 255) & ~(size_t)255;
    unsigned short* zb2 = (unsigned short*)(ws + off);    off += ((size_t)N_AGENTS * FC2 * 2 + 255) & ~(size_t)255;

    // ---- single zero-init memset ----
    hipMemsetAsync(zero_base, 0, zero_bytes, stream);

    // ---- graph prep / CSR build + weight transpose ----
    prep1w_k<<<PREP1_BLOCKS + WTR_BLOCKS, 256, 0, stream>>>(agent, nid, dstp, deg,
                                                            Wgcn, W1, W2, Wmu,
                                                            wgcn_t, w1_t, w2_t, wmu_t);
    prep2_k<<<(N_NODES + 255) / 256, 256, 0, stream>>>(nid, list, cnt, deg, rowbeg, etot, dis);
    fill_k<<<(N_EDGES + 255) / 256, 256, 0, stream>>>(srcp, dstp, nid, rowbeg, fill, ebuf);

    // ---- aggregate raw x per needed node ----
    accumx_k<<<N_AGENTS, 256, 0, stream>>>(cnt, list, rowbeg, deg, ebuf, dis, x, agg);

    // ---- GCN layer: h_node = relu(agg @ Wgcn + bgcn) ----
    {
        dim3 grid(HID / 128, N_AGENTS / 64);
        gemm_gcn_k<<<grid, 256, 0, stream>>>(agg, wgcn_t, bgcn, h_node);
    }

    // ---- FC1 (gather fused) + bias -> zb, and LN stats via atomics ----
    {
        dim3 grid(FC1 / BN, N_AGENTS / BM);
        gemm_fc1_k<<<grid, 256, 0, stream>>>(h_node, agent, nid, w1_t, b1, zb,
                                             rowsum, rowsumsq);
    }

    // ---- FC2 with LN1 applied during A-staging -> zb2 ----
    {
        dim3 grid(FC2 / 128, N_AGENTS / 64);
        gemm_fc2ln_k<<<grid, 256, 0, stream>>>(zb, rowsum, rowsumsq, g1, be1,
                                               w2_t, b2, zb2);
    }

    // ---- LN2 + ReLU + head ----
    ln2head_k<<<N_AGENTS / 16, 256, 0, stream>>>(zb2, g2, be2, wmu_t, bmu, out);
}